// Round 1
// 2329.491 us; speedup vs baseline: 1.3235x; 1.3235x over previous
//
#include <hip/hip_runtime.h>

#define STYLE_EPS 1e-4f

typedef __bf16 bf16x8 __attribute__((ext_vector_type(8)));
typedef float f32x4 __attribute__((ext_vector_type(4)));

// ---------------------------------------------------------------- reductions
__device__ __forceinline__ float block_reduce_sum(float v) {
  __shared__ float ws[8];
  #pragma unroll
  for (int off = 32; off > 0; off >>= 1) v += __shfl_down(v, off, 64);
  __syncthreads();                       // protect ws across repeated calls
  int lane = threadIdx.x & 63, wid = threadIdx.x >> 6;
  if (lane == 0) ws[wid] = v;
  __syncthreads();
  float s = 0.f;
  int nw = (blockDim.x + 63) >> 6;
  for (int i = 0; i < nw; ++i) s += ws[i];
  return s;
}

// out[row] = mean(in[row][0..K)) ; grid = nrows, block = 256
__global__ void row_mean_kernel(const float* __restrict__ in, float* __restrict__ out, int K) {
  size_t row = blockIdx.x;
  const float4* p4 = (const float4*)(in + row * (size_t)K);
  int K4 = K >> 2;
  float s = 0.f;
  for (int i = threadIdx.x; i < K4; i += blockDim.x) {
    float4 v = p4[i];
    s += (v.x + v.y) + (v.z + v.w);
  }
  s = block_reduce_sum(s);
  if (threadIdx.x == 0) out[row] = s / (float)K;
}

// ------------------------------------------------- split-bf16 MFMA Gram
// srm[b] += X_tile_i @ X_tile_j^T over one K chunk, via 3-term bf16 split:
//   x = hi + lo (hi = trunc-bf16(x), lo = bf16(x - hi));  X X^T ~= HH^T + HL^T + LH^T
// Dropped LL^T and lo rounding are ~1e-7 relative on cov entries (fp32-noise level).
// grid: (nchunks, 3 tile-pairs {(0,0),(0,1),(1,1)}, nbatch); block 256 = 4 waves.
// Block tile 128x128, wave tile 64x64 (4x4 frags of 16x16), K-step 64.
// LDS row-major [128 rows][64 k] bf16, XOR-swizzled (byte ^= (row&7)<<4) so
// column-slice ds_read_b128 (16 rows, same k) is 2-way/free (G4/T2).
// Gram symmetry makes any A/B-operand transpose or k-permutation harmless;
// only the C/D mapping (col=lane&15, row=(lane>>4)*4+reg, m89) must be right.

__device__ __forceinline__ uint pack2hi(uint u0, uint u1) {
  // u32 = (bf16(u1) << 16) | bf16(u0)   (truncating round)
  return __builtin_amdgcn_perm(u1, u0, 0x07060302u);
}

__device__ __forceinline__ void cvt_span(float4 v0, float4 v1, uint4& h, uint4& l) {
  uint b0 = __float_as_uint(v0.x), b1 = __float_as_uint(v0.y);
  uint b2 = __float_as_uint(v0.z), b3 = __float_as_uint(v0.w);
  uint b4 = __float_as_uint(v1.x), b5 = __float_as_uint(v1.y);
  uint b6 = __float_as_uint(v1.z), b7 = __float_as_uint(v1.w);
  h.x = pack2hi(b0, b1); h.y = pack2hi(b2, b3);
  h.z = pack2hi(b4, b5); h.w = pack2hi(b6, b7);
  float l0 = v0.x - __uint_as_float(b0 & 0xFFFF0000u);
  float l1 = v0.y - __uint_as_float(b1 & 0xFFFF0000u);
  float l2 = v0.z - __uint_as_float(b2 & 0xFFFF0000u);
  float l3 = v0.w - __uint_as_float(b3 & 0xFFFF0000u);
  float l4 = v1.x - __uint_as_float(b4 & 0xFFFF0000u);
  float l5 = v1.y - __uint_as_float(b5 & 0xFFFF0000u);
  float l6 = v1.z - __uint_as_float(b6 & 0xFFFF0000u);
  float l7 = v1.w - __uint_as_float(b7 & 0xFFFF0000u);
  l.x = pack2hi(__float_as_uint(l0), __float_as_uint(l1));
  l.y = pack2hi(__float_as_uint(l2), __float_as_uint(l3));
  l.z = pack2hi(__float_as_uint(l4), __float_as_uint(l5));
  l.w = pack2hi(__float_as_uint(l6), __float_as_uint(l7));
}

__global__ __launch_bounds__(256, 2)
void gram_mfma_kernel(const float* __restrict__ X, float* __restrict__ srm,
                      int K, int kchunk) {
  // 4 x 16 KB = 64 KB -> 2 blocks/CU
  __shared__ __align__(16) char ldsAh[16384];
  __shared__ __align__(16) char ldsAl[16384];
  __shared__ __align__(16) char ldsBh[16384];
  __shared__ __align__(16) char ldsBl[16384];

  const int pair = blockIdx.y;
  const int ti = (pair == 2) ? 1 : 0;
  const int tj = (pair == 0) ? 0 : 1;
  const bool diag = (ti == tj);
  const int b = blockIdx.z;
  const float* __restrict__ Xb = X + (size_t)b * 256 * (size_t)K;
  const float* __restrict__ Ab = Xb + (size_t)(ti * 128) * (size_t)K;
  const float* __restrict__ Bb = Xb + (size_t)(tj * 128) * (size_t)K;
  const int k0 = blockIdx.x * kchunk;

  const int t = threadIdx.x;
  const int lane = t & 63, wid = t >> 6;
  const int wr = (wid >> 1) * 64;          // wave row base within 128-tile
  const int wc = (wid & 1) * 64;           // wave col base within 128-tile
  const int srow = t >> 3;                 // staging: base row 0..31
  const int sspan = t & 7;                 // staging: 8-elem span 0..7

  f32x4 acc[4][4];
  #pragma unroll
  for (int m = 0; m < 4; ++m)
    #pragma unroll
    for (int n = 0; n < 4; ++n) acc[m][n] = (f32x4){0.f, 0.f, 0.f, 0.f};

  const float* pA = Ab + (size_t)srow * K + k0 + sspan * 8;
  const float* pB = Bb + (size_t)srow * K + k0 + sspan * 8;

  for (int kk = 0; kk < kchunk; kk += 64) {
    // ---- global loads (regs only; LDS from prev iter still being read) ----
    float4 ra[8], rb[8];
    #pragma unroll
    for (int rep = 0; rep < 4; ++rep) {
      const float* p = pA + (size_t)(rep * 32) * K + kk;
      ra[2 * rep]     = *(const float4*)(p);
      ra[2 * rep + 1] = *(const float4*)(p + 4);
    }
    if (!diag) {
      #pragma unroll
      for (int rep = 0; rep < 4; ++rep) {
        const float* p = pB + (size_t)(rep * 32) * K + kk;
        rb[2 * rep]     = *(const float4*)(p);
        rb[2 * rep + 1] = *(const float4*)(p + 4);
      }
    }
    __syncthreads();   // prev compute done -> safe to overwrite LDS
    // ---- convert + swizzled LDS write ----
    #pragma unroll
    for (int rep = 0; rep < 4; ++rep) {
      int r = srow + rep * 32;
      int off = (r << 7) + ((sspan << 4) ^ ((r & 7) << 4));
      uint4 h, l;
      cvt_span(ra[2 * rep], ra[2 * rep + 1], h, l);
      *(uint4*)(ldsAh + off) = h;
      *(uint4*)(ldsAl + off) = l;
      if (!diag) {
        cvt_span(rb[2 * rep], rb[2 * rep + 1], h, l);
        *(uint4*)(ldsBh + off) = h;
        *(uint4*)(ldsBl + off) = l;
      }
    }
    __syncthreads();
    // ---- MFMA: 2 k-sub-steps of 32 ----
    const char* BH = diag ? ldsAh : ldsBh;
    const char* BL = diag ? ldsAl : ldsBl;
    #pragma unroll
    for (int ks = 0; ks < 2; ++ks) {
      const int kb = ks * 64 + ((lane >> 4) << 4);  // this lane's 8-elem byte off
      bf16x8 ah[4], al[4];
      #pragma unroll
      for (int m = 0; m < 4; ++m) {
        int r = wr + m * 16 + (lane & 15);
        int o = (r << 7) + (kb ^ ((r & 7) << 4));
        ah[m] = *(const bf16x8*)(ldsAh + o);
        al[m] = *(const bf16x8*)(ldsAl + o);
      }
      #pragma unroll
      for (int n = 0; n < 4; ++n) {
        int r = wc + n * 16 + (lane & 15);
        int o = (r << 7) + (kb ^ ((r & 7) << 4));
        bf16x8 bh = *(const bf16x8*)(BH + o);
        bf16x8 bl = *(const bf16x8*)(BL + o);
        #pragma unroll
        for (int m = 0; m < 4; ++m) {
          acc[m][n] = __builtin_amdgcn_mfma_f32_16x16x32_bf16(ah[m], bh, acc[m][n], 0, 0, 0);
          acc[m][n] = __builtin_amdgcn_mfma_f32_16x16x32_bf16(ah[m], bl, acc[m][n], 0, 0, 0);
          acc[m][n] = __builtin_amdgcn_mfma_f32_16x16x32_bf16(al[m], bh, acc[m][n], 0, 0, 0);
        }
      }
    }
  }
  // ---- epilogue: C/D layout col=lane&15, row=(lane>>4)*4+q (m89) ----
  float* dst = srm + ((size_t)b << 16);
  const int rq = (lane >> 4) << 2;
  const int cl = lane & 15;
  #pragma unroll
  for (int m = 0; m < 4; ++m) {
    #pragma unroll
    for (int n = 0; n < 4; ++n) {
      #pragma unroll
      for (int q = 0; q < 4; ++q) {
        int r = ti * 128 + wr + m * 16 + rq + q;
        int c = tj * 128 + wc + n * 16 + cl;
        atomicAdd(dst + (size_t)r * 256 + c, acc[m][n][q]);
      }
    }
  }
}

// cov = srm*inv_n - outer(mean,mean) + eps*I, mirroring the uncomputed (1,0) tile
__global__ void cov_finalize_kernel(const float* __restrict__ srm, const float* __restrict__ mean,
                                    float* __restrict__ cov, float inv_n, float eps) {
  int m = blockIdx.y;
  int idx = blockIdx.x * 256 + threadIdx.x;   // 0..65535
  int c = idx >> 8, d = idx & 255;
  size_t base = (size_t)m << 16;
  float s = ((c >> 7) > (d >> 7)) ? srm[base + ((size_t)d << 8) + c] : srm[base + idx];
  float v = s * inv_n - mean[m * 256 + c] * mean[m * 256 + d];
  if (c == d) v += eps;
  cov[base + idx] = v;
}

// sumsq[m] = ||A_m||_F^2 ; grid = nmat, block 256
__global__ void frob_kernel(const float* __restrict__ A, float* __restrict__ sumsq) {
  int m = blockIdx.x;
  const float4* p = (const float4*)(A + ((size_t)m << 16));
  float s = 0.f;
  for (int i = threadIdx.x; i < 16384; i += 256) {
    float4 v = p[i];
    s += v.x * v.x + v.y * v.y + v.z * v.z + v.w * v.w;
  }
  s = block_reduce_sum(s);
  if (threadIdx.x == 0) sumsq[m] = s;
}

// Y = A * rsqrt(sumsq) ; Z = I ; grid (256, nmat)
__global__ void ns_init_kernel(const float* __restrict__ A, const float* __restrict__ sumsq,
                               float* __restrict__ Y, float* __restrict__ Z) {
  int m = blockIdx.y;
  int idx = blockIdx.x * 256 + threadIdx.x;
  float rn = rsqrtf(sumsq[m]);
  size_t o = ((size_t)m << 16) + idx;
  int c = idx >> 8, d = idx & 255;
  Y[o] = A[o] * rn;
  Z[o] = (c == d) ? 1.f : 0.f;
}

// Out = Y * sumsq^(1/4)   (= y * sqrt(frob_norm)) ; grid (256, nmat)
__global__ void ns_final_kernel(const float* __restrict__ Y, const float* __restrict__ sumsq,
                                float* __restrict__ Out) {
  int m = blockIdx.y;
  float f = sqrtf(sqrtf(sumsq[m]));
  size_t o = ((size_t)m << 16) + blockIdx.x * 256 + threadIdx.x;
  Out[o] = Y[o] * f;
}

// ------------------------------------------------- 256x256x256 fp32 gemm tile
// C_tile = alpha*(A@B)_tile (+ diag_add on diagonal). 64x64 tile, 4x4 micro.
__device__ __forceinline__ void gemm64_tile(const float* __restrict__ A,
                                            const float* __restrict__ B,
                                            float* __restrict__ C,
                                            float alpha, float diag_add, int tile) {
  __shared__ float As[32][64];
  __shared__ float Bs[32][64];
  const int tm = tile >> 2, tn = tile & 3;
  const int t = threadIdx.x;
  const int tx = t & 15, ty = t >> 4;
  const int arow = t >> 2, akq = (t & 3) * 8;
  const int brow = t >> 3, bnq = (t & 7) * 8;
  float acc[4][4];
  #pragma unroll
  for (int i = 0; i < 4; ++i)
    #pragma unroll
    for (int j = 0; j < 4; ++j) acc[i][j] = 0.f;

  for (int kk = 0; kk < 256; kk += 32) {
    float4 a0 = *(const float4*)(A + (size_t)(tm * 64 + arow) * 256 + kk + akq);
    float4 a1 = *(const float4*)(A + (size_t)(tm * 64 + arow) * 256 + kk + akq + 4);
    float4 b0 = *(const float4*)(B + (size_t)(kk + brow) * 256 + tn * 64 + bnq);
    float4 b1 = *(const float4*)(B + (size_t)(kk + brow) * 256 + tn * 64 + bnq + 4);
    __syncthreads();
    As[akq + 0][arow] = a0.x; As[akq + 1][arow] = a0.y; As[akq + 2][arow] = a0.z; As[akq + 3][arow] = a0.w;
    As[akq + 4][arow] = a1.x; As[akq + 5][arow] = a1.y; As[akq + 6][arow] = a1.z; As[akq + 7][arow] = a1.w;
    *(float4*)&Bs[brow][bnq] = b0;
    *(float4*)&Bs[brow][bnq + 4] = b1;
    __syncthreads();
    #pragma unroll 8
    for (int k = 0; k < 32; ++k) {
      float4 av4 = *(const float4*)&As[k][ty * 4];
      float4 bv4 = *(const float4*)&Bs[k][tx * 4];
      float av[4] = {av4.x, av4.y, av4.z, av4.w};
      float bv[4] = {bv4.x, bv4.y, bv4.z, bv4.w};
      #pragma unroll
      for (int i = 0; i < 4; ++i)
        #pragma unroll
        for (int j = 0; j < 4; ++j)
          acc[i][j] = fmaf(av[i], bv[j], acc[i][j]);
    }
  }
  #pragma unroll
  for (int i = 0; i < 4; ++i) {
    int r = tm * 64 + ty * 4 + i;
    #pragma unroll
    for (int j = 0; j < 4; ++j) {
      int c = tn * 64 + tx * 4 + j;
      float v = alpha * acc[i][j];
      if (r == c) v += diag_add;
      C[(size_t)r * 256 + c] = v;
    }
  }
}

// T = 1.5*I - 0.5*(Z@Y) ; grid (16, nmat)
__global__ void ns_t_kernel(const float* __restrict__ Z, const float* __restrict__ Y,
                            float* __restrict__ T) {
  size_t o = (size_t)blockIdx.y << 16;
  gemm64_tile(Z + o, Y + o, T + o, -0.5f, 1.5f, blockIdx.x);
}

// Yn = Y@T (m < nmat) ; Zn = T@Z (m >= nmat) ; grid (16, 2*nmat)
__global__ void ns_yz_kernel(const float* __restrict__ Y, const float* __restrict__ Z,
                             const float* __restrict__ T,
                             float* __restrict__ Yn, float* __restrict__ Zn, int nmat) {
  int m = blockIdx.y;
  const float* Ap; const float* Bp; float* Cp;
  if (m < nmat) { size_t o = (size_t)m << 16; Ap = Y + o; Bp = T + o; Cp = Yn + o; }
  else          { size_t o = (size_t)(m - nmat) << 16; Ap = T + o; Bp = Z + o; Cp = Zn + o; }
  gemm64_tile(Ap, Bp, Cp, 1.f, 0.f, blockIdx.x);
}

// C[m] = A[m*sA] @ B[m*sB] ; grid (16, nmat)
__global__ void gemm_stride_kernel(const float* __restrict__ A, long sA,
                                   const float* __restrict__ B, long sB,
                                   float* __restrict__ C, long sC) {
  int m = blockIdx.y;
  gemm64_tile(A + (size_t)m * sA, B + (size_t)m * sB, C + (size_t)m * sC, 1.f, 0.f, blockIdx.x);
}

// out[0] = mean((meanB-meanT)^2) + mean(diag(covT + covB - 2*sqrtM)) ; 1 block
__global__ void loss_kernel(const float* __restrict__ meanB, const float* __restrict__ meanT,
                            const float* __restrict__ covT, const float* __restrict__ covB,
                            const float* __restrict__ sqrtM, float* __restrict__ out) {
  float s1 = 0.f, s2 = 0.f;
  for (int i = threadIdx.x; i < 2048; i += 256) {
    int b = i >> 8, c = i & 255;
    float dm = meanB[i] - meanT[c];
    s1 += dm * dm;
    size_t di = ((size_t)b << 16) + (size_t)c * 257;
    s2 += covT[(size_t)c * 257] + covB[di] - 2.f * sqrtM[di];
  }
  s1 = block_reduce_sum(s1);
  s2 = block_reduce_sum(s2);
  if (threadIdx.x == 0) out[0] = (s1 + s2) / 2048.f;
}

// ------------------------------------------------------------------- launch
extern "C" void kernel_launch(void* const* d_in, const int* in_sizes, int n_in,
                              void* d_out, int out_size, void* d_ws, size_t ws_size,
                              hipStream_t stream) {
  const float* x  = (const float*)d_in[0];   // [8,256,256,256]
  const float* tf = (const float*)d_in[1];   // [256,16384]
  float* out = (float*)d_out;
  float* W = (float*)d_ws;

  const size_t M = 65536;   // 256*256
  float* meanT = W;                       // 256
  float* meanB = meanT + 256;             // 2048
  float* srmT  = meanB + 2048;            // 65536
  float* covT  = srmT + M;                // 65536
  float* srmB  = covT + M;                // 8*65536
  float* covB  = srmB + 8 * M;            // 8*65536
  float* covTs = covB + 8 * M;            // 65536
  float* Ya    = covTs + M;               // 8*65536
  float* Yb    = Ya + 8 * M;
  float* Za    = Yb + 8 * M;
  float* Zb    = Za + 8 * M;
  float* Tm    = Zb + 8 * M;
  float* P1    = Tm + 8 * M;              // sandwich temp, later sqrtM
  float* Mm    = P1 + 8 * M;              // sandwich result
  float* sumsq = Mm + 8 * M;              // 16

  // zero the atomic accumulators (ws is poisoned 0xAA before every call)
  hipMemsetAsync(srmT, 0, M * sizeof(float), stream);
  hipMemsetAsync(srmB, 0, 8 * M * sizeof(float), stream);

  // ---- target branch ----
  row_mean_kernel<<<256, 256, 0, stream>>>(tf, meanT, 16384);
  gram_mfma_kernel<<<dim3(32, 3, 1), 256, 0, stream>>>(tf, srmT, 16384, 512);
  cov_finalize_kernel<<<dim3(256, 1), 256, 0, stream>>>(srmT, meanT, covT, 1.f / 16384.f, STYLE_EPS);

  // NS(covT), batch=1
  frob_kernel<<<1, 256, 0, stream>>>(covT, sumsq);
  ns_init_kernel<<<dim3(256, 1), 256, 0, stream>>>(covT, sumsq, Ya, Za);
  {
    float *y = Ya, *yn = Yb, *z = Za, *zn = Zb;
    for (int it = 0; it < 12; ++it) {
      ns_t_kernel<<<dim3(16, 1), 256, 0, stream>>>(z, y, Tm);
      ns_yz_kernel<<<dim3(16, 2), 256, 0, stream>>>(y, z, Tm, yn, zn, 1);
      float* tp;
      tp = y; y = yn; yn = tp;
      tp = z; z = zn; zn = tp;
    }
    ns_final_kernel<<<dim3(256, 1), 256, 0, stream>>>(y, sumsq, covTs);
  }

  // ---- batch branch ----
  row_mean_kernel<<<2048, 256, 0, stream>>>(x, meanB, 65536);
  gram_mfma_kernel<<<dim3(32, 3, 8), 256, 0, stream>>>(x, srmB, 65536, 2048);
  cov_finalize_kernel<<<dim3(256, 8), 256, 0, stream>>>(srmB, meanB, covB, 1.f / 65536.f, STYLE_EPS);

  // Mm = covTs @ covB @ covTs
  gemm_stride_kernel<<<dim3(16, 8), 256, 0, stream>>>(covTs, 0L, covB, (long)M, P1, (long)M);
  gemm_stride_kernel<<<dim3(16, 8), 256, 0, stream>>>(P1, (long)M, covTs, 0L, Mm, (long)M);

  // NS(Mm), batch=8
  frob_kernel<<<8, 256, 0, stream>>>(Mm, sumsq);
  ns_init_kernel<<<dim3(256, 8), 256, 0, stream>>>(Mm, sumsq, Ya, Za);
  {
    float *y = Ya, *yn = Yb, *z = Za, *zn = Zb;
    for (int it = 0; it < 12; ++it) {
      ns_t_kernel<<<dim3(16, 8), 256, 0, stream>>>(z, y, Tm);
      ns_yz_kernel<<<dim3(16, 16), 256, 0, stream>>>(y, z, Tm, yn, zn, 8);
      float* tp;
      tp = y; y = yn; yn = tp;
      tp = z; z = zn; zn = tp;
    }
    ns_final_kernel<<<dim3(256, 8), 256, 0, stream>>>(y, sumsq, P1);  // P1 := sqrt_term
  }

  // ---- loss ----
  loss_kernel<<<1, 256, 0, stream>>>(meanB, meanT, covT, covB, P1, out);
}